// Round 2
// baseline (461.247 us; speedup 1.0000x reference)
//
#include <hip/hip_runtime.h>

// SparseInputLayer: inputs [B, ND*(1+NS)] fp32.
//  - cols [0,64): channel indices (float-encoded ints in [0,384))
//  - cols [64, 64+64*121): data rows x[b][j][s]
// out[b][c][s] = sum_{j: idx[b][j]==c} x[b][j][s], shape [2048,384,121,1] fp32.
//
// Strategy: one block per batch. Build per-channel 64-bit "which j maps here"
// bitmask in LDS, then stream the output via a (channel, slot) decomposition:
//   w >> 5 = c, w & 31 = t   (no division anywhere)
//   t in [0,30): quad store at s0 = 4t          (covers s = 0..119)
//   t == 30:     OVERLAPPING quad at s0 = 117   (covers s = 117..120)
//   t == 31:     idle (2 of 64 lanes)
// The overlap bytes (s=117..119) are written by both t=29 and t=30 with
// bit-identical values (same mask, same ctz accumulation order), so the
// double-write is benign. This kills the round-1 straddle slow path entirely:
// no divisions, no divergent boundary path, one ds_read_b64 + one
// global_store_dwordx4 per 4 output elements.

#define BATCH 2048
#define N_DENSE 64
#define N_SAMPLES 121
#define N_CHANNELS 384
#define ROW_IN (N_DENSE * (1 + N_SAMPLES)) // 7808 floats per input row
#define ROW_OUT (N_CHANNELS * N_SAMPLES)   // 46464 floats per output row
#define BLOCK 256
#define SLOTS 32                            // 30 quads + overlap quad + idle
#define NWORK (N_CHANNELS * SLOTS)          // 12288 -> 48 iters at BLOCK=256

// dword-aligned 4-float vector: channel stride is 484 B, so quads are only
// guaranteed 4B-aligned; gfx9+ handles unaligned global dwordx4 in HW.
typedef float floatx4 __attribute__((ext_vector_type(4), aligned(4)));

__global__ __launch_bounds__(BLOCK) void sparse_scatter_kernel(
    const float* __restrict__ in, float* __restrict__ out) {
  __shared__ unsigned long long mask[N_CHANNELS];

  const int b = blockIdx.x;
  const int tid = threadIdx.x;

  // init per-channel membership masks
  for (int c = tid; c < N_CHANNELS; c += BLOCK) mask[c] = 0ull;
  __syncthreads();

  // threads 0..63 each own one dense slot j; set bit j in its channel's mask
  if (tid < N_DENSE) {
    const int c = (int)in[(size_t)b * ROW_IN + tid];
    atomicOr(&mask[c], 1ull << tid);
  }
  __syncthreads();

  const float* __restrict__ x = in + (size_t)b * ROW_IN + N_DENSE; // [64][121]
  float* __restrict__ o = out + (size_t)b * ROW_OUT;               // [384][121]

  for (int w = tid; w < NWORK; w += BLOCK) {
    const int c = w >> 5;       // channel
    const int t = w & 31;       // slot within channel
    if (t == 31) continue;      // idle lane
    const int s0 = (t == 30) ? 117 : (t << 2);

    unsigned long long m = mask[c]; // LDS broadcast (<=2 addresses per wave)
    floatx4 v = {0.f, 0.f, 0.f, 0.f};
    while (m) {
      const int j = __builtin_ctzll(m);
      m &= m - 1;
      const float* __restrict__ xp = x + j * N_SAMPLES + s0; // L1/L2-resident slab
      v.x += xp[0];
      v.y += xp[1];
      v.z += xp[2];
      v.w += xp[3];
    }
    *reinterpret_cast<floatx4*>(o + c * N_SAMPLES + s0) = v;
  }
}

extern "C" void kernel_launch(void* const* d_in, const int* in_sizes, int n_in,
                              void* d_out, int out_size, void* d_ws, size_t ws_size,
                              hipStream_t stream) {
  const float* in = (const float*)d_in[0];
  float* out = (float*)d_out;
  sparse_scatter_kernel<<<BATCH, BLOCK, 0, stream>>>(in, out);
}